// Round 11
// baseline (315.542 us; speedup 1.0000x reference)
//
#include <hip/hip_runtime.h>
#include <hip/hip_fp16.h>
#include <math.h>

#define N_NODES 50000
#define E_EDGES 800000
#define ETOT    (E_EDGES + N_NODES)

// bucketed scatter params
#define BUCK_SHIFT 9
#define BUCK_SZ   (1 << BUCK_SHIFT)                               // 512
#define NBUCK ((N_NODES + BUCK_SZ - 1) >> BUCK_SHIFT)             // 98
#define BS_EPT 16
#define BS_THREADS 256
#define BS_EPB (BS_THREADS * BS_EPT)                              // 4096
#define BS_NBLK ((ETOT + BS_EPB - 1) / BS_EPB)

// gemm0 grid / hist slice
#define GEMM0_GRID ((N_NODES + 63) / 64)                          // 782
#define HPB ((ETOT + GEMM0_GRID - 1) / GEMM0_GRID)                // 1088

// ---------------------------------------------------------------------------
// Layer-0 GEMM + alpha epilogue + fused edge-bucket histogram.
// DIN=128, DOUT=64, BM=64. Xl reused as hist scratch after the k-loop.
// ---------------------------------------------------------------------------
__global__ __launch_bounds__(256)
void gemm0_hist_kernel(const float* __restrict__ X, const float* __restrict__ W,
                       const float* __restrict__ a_s, const float* __restrict__ a_d,
                       const int* __restrict__ ei, int* __restrict__ bcnt,
                       __half* __restrict__ H16, float* __restrict__ asrc,
                       float* __restrict__ adst)
{
    constexpr int DIN = 128, DOUT = 64;
    constexpr int COLG = DOUT / 4;     // 16
    constexpr int BM   = 64;
    constexpr int K4   = DIN / 4;

    __shared__ float Xl[BM * DIN];     // 32 KB
    __shared__ float Wl[DIN * DOUT];   // 32 KB

    const int tid = threadIdx.x;
    const int row0b = blockIdx.x * BM;

    for (int i = tid; i < DIN * DOUT / 4; i += 256)
        ((float4*)Wl)[i] = ((const float4*)W)[i];

    for (int i = tid; i < BM * K4; i += 256) {
        int r  = i / K4;
        int j  = i % K4;
        int gr = row0b + r;
        float4 v = make_float4(0.f, 0.f, 0.f, 0.f);
        if (gr < N_NODES) v = ((const float4*)X)[gr * K4 + j];
        *(float4*)&Xl[r * DIN + ((j ^ ((r >> 2) & 7)) << 2)] = v;
    }
    __syncthreads();

    const int tx = tid % COLG;
    const int ty = tid / COLG;
    const int r0 = ty * 4;
    const int c0 = tx * 4;
    const int swz = ty & 7;

    float acc[4][4] = {};
    for (int kk = 0; kk < DIN; kk += 4) {
        float a[4][4], w[4][4];
        const int jk = ((kk >> 2) ^ swz) << 2;
#pragma unroll
        for (int i = 0; i < 4; ++i)
            *(float4*)a[i] = *(const float4*)&Xl[(r0 + i) * DIN + jk];
#pragma unroll
        for (int j = 0; j < 4; ++j)
            *(float4*)w[j] = *(const float4*)&Wl[(kk + j) * DOUT + c0];
#pragma unroll
        for (int i = 0; i < 4; ++i)
#pragma unroll
            for (int j = 0; j < 4; ++j)
                acc[i][j] = fmaf(a[i][0], w[0][j],
                            fmaf(a[i][1], w[1][j],
                            fmaf(a[i][2], w[2][j],
                            fmaf(a[i][3], w[3][j], acc[i][j]))));
    }

    float as4[4], ad4[4];
    *(float4*)as4 = *(const float4*)&a_s[c0];
    *(float4*)ad4 = *(const float4*)&a_d[c0];

#pragma unroll
    for (int i = 0; i < 4; ++i) {
        const int gr = row0b + r0 + i;
        float ps = acc[i][0] * as4[0] + acc[i][1] * as4[1] +
                   acc[i][2] * as4[2] + acc[i][3] * as4[3];
        float pd = acc[i][0] * ad4[0] + acc[i][1] * ad4[1] +
                   acc[i][2] * ad4[2] + acc[i][3] * ad4[3];
#pragma unroll
        for (int off = COLG / 2; off >= 1; off >>= 1) {
            ps += __shfl_xor(ps, off, 64);
            pd += __shfl_xor(pd, off, 64);
        }
        if (gr < N_NODES) {
            __half2 p01 = __floats2half2_rn(acc[i][0], acc[i][1]);
            __half2 p23 = __floats2half2_rn(acc[i][2], acc[i][3]);
            uint2 pk;
            pk.x = *(unsigned int*)&p01;
            pk.y = *(unsigned int*)&p23;
            *(uint2*)&H16[gr * DOUT + c0] = pk;
            if (tx == 0) { asrc[gr] = ps; adst[gr] = pd; }
        }
    }

    // ---- fused hist: reuse Xl as LDS counters (Xl dead after k-loop) ----
    __syncthreads();
    int* lh = (int*)Xl;
    for (int i = tid; i < NBUCK; i += 256) lh[i] = 0;
    __syncthreads();
    const int h0 = blockIdx.x * HPB;
    const int hend = min(h0 + HPB, ETOT);
    for (int eid = h0 + tid; eid < hend; eid += 256) {
        int dst = (eid < E_EDGES) ? ei[E_EDGES + eid] : (eid - E_EDGES);
        atomicAdd(&lh[dst >> BUCK_SHIFT], 1);
    }
    __syncthreads();
    for (int i = tid; i < NBUCK; i += 256)
        if (lh[i] > 0) atomicAdd(&bcnt[i], lh[i]);
}

// ---------------------------------------------------------------------------
// CSR build rest: scan98 -> binscatter -> bucket_sort (round-8 pipeline)
// ---------------------------------------------------------------------------
__global__ __launch_bounds__(128)
void scan98_kernel(const int* __restrict__ bcnt, int* __restrict__ cur,
                   int* __restrict__ cur0)
{
    __shared__ int lds[128];
    const int t = threadIdx.x;
    const int v = (t < NBUCK) ? bcnt[t] : 0;
    lds[t] = v;
    __syncthreads();
    for (int off = 1; off < 128; off <<= 1) {
        int u = (t >= off) ? lds[t - off] : 0;
        __syncthreads();
        lds[t] += u;
        __syncthreads();
    }
    if (t < NBUCK) { cur[t] = lds[t] - v; cur0[t] = lds[t] - v; }
}

__global__ __launch_bounds__(BS_THREADS)
void binscatter_kernel(const int* __restrict__ ei, int* __restrict__ cur,
                       unsigned int* __restrict__ tmp)
{
    __shared__ int lcnt[NBUCK];
    __shared__ int lbase[NBUCK];
    const int t = threadIdx.x;
    for (int i = t; i < NBUCK; i += BS_THREADS) lcnt[i] = 0;
    __syncthreads();

    const int e0 = blockIdx.x * BS_EPB;
    unsigned int pk[BS_EPT];
    int rk[BS_EPT];
    int bk[BS_EPT];
#pragma unroll
    for (int k = 0; k < BS_EPT; ++k) {
        const int eid = e0 + k * BS_THREADS + t;
        bk[k] = -1;
        if (eid < ETOT) {
            int src, dst;
            if (eid < E_EDGES) { src = ei[eid]; dst = ei[E_EDGES + eid]; }
            else               { src = dst = eid - E_EDGES; }
            bk[k] = dst >> BUCK_SHIFT;
            pk[k] = ((unsigned int)dst << 16) | (unsigned int)src;
            rk[k] = atomicAdd(&lcnt[bk[k]], 1);
        }
    }
    __syncthreads();
    for (int i = t; i < NBUCK; i += BS_THREADS)
        if (lcnt[i] > 0) lbase[i] = atomicAdd(&cur[i], lcnt[i]);
    __syncthreads();
#pragma unroll
    for (int k = 0; k < BS_EPT; ++k)
        if (bk[k] >= 0) tmp[lbase[bk[k]] + rk[k]] = pk[k];
}

__global__ __launch_bounds__(BUCK_SZ)
void bucket_sort_kernel(const unsigned int* __restrict__ tmp,
                        const int* __restrict__ cur0,
                        const int* __restrict__ bcnt,
                        unsigned int* __restrict__ csr_pk,
                        int* __restrict__ offs)
{
    __shared__ int lcnt[BUCK_SZ];
    __shared__ int loff[BUCK_SZ];
    __shared__ int lcur[BUCK_SZ];
    const int bk = blockIdx.x;
    const int t  = threadIdx.x;
    const int base = cur0[bk];
    const int cnt  = bcnt[bk];

    lcnt[t] = 0;
    __syncthreads();
    for (int i = t; i < cnt; i += BUCK_SZ)
        atomicAdd(&lcnt[(tmp[base + i] >> 16) & (BUCK_SZ - 1)], 1);
    __syncthreads();

    const int v = lcnt[t];
    loff[t] = v;
    __syncthreads();
    for (int off = 1; off < BUCK_SZ; off <<= 1) {
        int u = (t >= off) ? loff[t - off] : 0;
        __syncthreads();
        loff[t] += u;
        __syncthreads();
    }
    const int excl = loff[t] - v;

    const int g = (bk << BUCK_SHIFT) + t;
    if (g <= N_NODES) offs[g] = base + excl;   // tail node writes offs[N]=ETOT

    lcur[t] = excl;
    __syncthreads();
    for (int i = t; i < cnt; i += BUCK_SZ) {
        const unsigned int pk = tmp[base + i];
        const int l = (pk >> 16) & (BUCK_SZ - 1);
        const int pos = atomicAdd(&lcur[l], 1);
        csr_pk[base + pos] = pk;
    }
}

// ---------------------------------------------------------------------------
// Fused layer boundary: aggregate 64 nodes of prev layer (DOUT_prev=64,
// relu) into LDS, then 64xDIN gemm + alpha for the next layer.
// One block = 64 output rows. Prev agg uses v5 structure (FL=8 x SLOTS=8).
// ---------------------------------------------------------------------------
template<int DOUT>   // next-layer dout: 64 or 32
__global__ __launch_bounds__(256)
void fused_agg_gemm_kernel(const int* __restrict__ offs,
                           const unsigned int* __restrict__ csr_pk,
                           const float* __restrict__ asrc_p,
                           const float* __restrict__ adst_p,
                           const __half* __restrict__ H16_p,
                           const float* __restrict__ b_p,
                           const float* __restrict__ W,
                           const float* __restrict__ a_s,
                           const float* __restrict__ a_d,
                           __half* __restrict__ H16_n,
                           float* __restrict__ asrc_n,
                           float* __restrict__ adst_n)
{
    constexpr int DIN = 64;
    constexpr int BM  = 64;
    __shared__ float Xl[BM * DIN];     // 16 KB
    __shared__ float Wl[DIN * DOUT];   // 16 or 8 KB

    const int tid = threadIdx.x;
    for (int i = tid; i < DIN * DOUT / 4; i += 256)
        ((float4*)Wl)[i] = ((const float4*)W)[i];

    // ---- phase 1: aggregate 64 nodes (4 waves x 16 iterations) ----
    const int wv   = tid >> 6;
    const int lane = tid & 63;
    const int fl   = lane & 7;         // FL = 8
    const int slot = lane >> 3;        // SLOTS = 8
    const int node0 = blockIdx.x * BM;
    const __half* __restrict__ Hf = H16_p + fl * 8;

    for (int it = 0; it < 16; ++it) {
        const int r = it * 4 + wv;
        const int node = node0 + r;
        float s = 0.f;
        float acc[8] = {};
        if (node < N_NODES) {
            const int beg = offs[node];
            const int end = offs[node + 1];
            const float adn = adst_p[node];
            int eid = beg + slot;
            bool valid = (eid < end);
            unsigned int pk = valid ? csr_pk[eid] : 0u;
            for (int cb = beg; cb < end; cb += 8) {
                const int nid = cb + 8 + slot;
                const bool nvalid = (nid < end);
                const unsigned int npk = nvalid ? csr_pk[nid] : 0u;
                float p = 0.f;
                uint4 h = make_uint4(0u, 0u, 0u, 0u);
                if (valid) {
                    const unsigned int src = pk & 0xffffu;
                    float v = asrc_p[src] + adn;
                    v = fmaxf(v, 0.2f * v);
                    p = __expf(fminf(v, 80.f));
                    h = *(const uint4*)(Hf + src * 64);
                }
                const float2 f0 = __half22float2(*(const __half2*)&h.x);
                const float2 f1 = __half22float2(*(const __half2*)&h.y);
                const float2 f2 = __half22float2(*(const __half2*)&h.z);
                const float2 f3 = __half22float2(*(const __half2*)&h.w);
                s += p;
                acc[0] = fmaf(p, f0.x, acc[0]);
                acc[1] = fmaf(p, f0.y, acc[1]);
                acc[2] = fmaf(p, f1.x, acc[2]);
                acc[3] = fmaf(p, f1.y, acc[3]);
                acc[4] = fmaf(p, f2.x, acc[4]);
                acc[5] = fmaf(p, f2.y, acc[5]);
                acc[6] = fmaf(p, f3.x, acc[6]);
                acc[7] = fmaf(p, f3.y, acc[7]);
                valid = nvalid;
                pk = npk;
            }
        }
#pragma unroll
        for (int off = 8; off < 64; off <<= 1) {
            s += __shfl_xor(s, off, 64);
#pragma unroll
            for (int j = 0; j < 8; ++j)
                acc[j] += __shfl_xor(acc[j], off, 64);
        }
        if (slot == 0) {
            float o[8];
            if (node < N_NODES) {
                const float inv = 1.f / s;
#pragma unroll
                for (int j = 0; j < 8; ++j)
                    o[j] = fmaxf(acc[j] * inv + b_p[fl * 8 + j], 0.f);  // relu
            } else {
#pragma unroll
                for (int j = 0; j < 8; ++j) o[j] = 0.f;
            }
            const int sw = (r >> 2) & 7;
            *(float4*)&Xl[r * DIN + (((fl * 2) ^ sw) << 2)] =
                make_float4(o[0], o[1], o[2], o[3]);
            *(float4*)&Xl[r * DIN + (((fl * 2 + 1) ^ sw) << 2)] =
                make_float4(o[4], o[5], o[6], o[7]);
        }
    }
    __syncthreads();

    // ---- phase 2: 64xDIN gemm + alpha epilogue ----
    constexpr int COLG = DOUT / 4;       // 16 or 8
    constexpr int ROWG = 256 / COLG;     // 16 or 32
    constexpr int RPT  = BM / ROWG;      // 4 or 2
    const int tx = tid % COLG;
    const int ty = tid / COLG;
    const int r0 = ty * RPT;
    const int c0 = tx * 4;
    const int swz = (r0 >> 2) & 7;

    float acg[RPT][4] = {};
    for (int kk = 0; kk < DIN; kk += 4) {
        float a[RPT][4], w[4][4];
        const int jk = ((kk >> 2) ^ swz) << 2;
#pragma unroll
        for (int i = 0; i < RPT; ++i)
            *(float4*)a[i] = *(const float4*)&Xl[(r0 + i) * DIN + jk];
#pragma unroll
        for (int j = 0; j < 4; ++j)
            *(float4*)w[j] = *(const float4*)&Wl[(kk + j) * DOUT + c0];
#pragma unroll
        for (int i = 0; i < RPT; ++i)
#pragma unroll
            for (int j = 0; j < 4; ++j)
                acg[i][j] = fmaf(a[i][0], w[0][j],
                            fmaf(a[i][1], w[1][j],
                            fmaf(a[i][2], w[2][j],
                            fmaf(a[i][3], w[3][j], acg[i][j]))));
    }

    float as4[4], ad4[4];
    *(float4*)as4 = *(const float4*)&a_s[c0];
    *(float4*)ad4 = *(const float4*)&a_d[c0];

#pragma unroll
    for (int i = 0; i < RPT; ++i) {
        const int gr = node0 + r0 + i;
        float ps = acg[i][0] * as4[0] + acg[i][1] * as4[1] +
                   acg[i][2] * as4[2] + acg[i][3] * as4[3];
        float pd = acg[i][0] * ad4[0] + acg[i][1] * ad4[1] +
                   acg[i][2] * ad4[2] + acg[i][3] * ad4[3];
#pragma unroll
        for (int off = COLG / 2; off >= 1; off >>= 1) {
            ps += __shfl_xor(ps, off, 64);
            pd += __shfl_xor(pd, off, 64);
        }
        if (gr < N_NODES) {
            __half2 p01 = __floats2half2_rn(acg[i][0], acg[i][1]);
            __half2 p23 = __floats2half2_rn(acg[i][2], acg[i][3]);
            uint2 pk;
            pk.x = *(unsigned int*)&p01;
            pk.y = *(unsigned int*)&p23;
            *(uint2*)&H16_n[gr * DOUT + c0] = pk;
            if (tx == 0) { asrc_n[gr] = ps; adst_n[gr] = pd; }
        }
    }
}

// ---------------------------------------------------------------------------
// Final node_agg (v5): inline score, 16B fp16 gathers, pk prefetch, tanh.
// ---------------------------------------------------------------------------
template<int DOUT, int ACT>
__global__ __launch_bounds__(256)
void node_agg_kernel(const int* __restrict__ offs,
                     const unsigned int* __restrict__ csr_pk,
                     const float* __restrict__ asrc,
                     const float* __restrict__ adst,
                     const __half* __restrict__ H16,
                     const float* __restrict__ b,
                     float* __restrict__ out)
{
    constexpr int FL    = DOUT / 8;    // 4 for dout=32
    constexpr int SLOTS = 64 / FL;     // 16
    const int wv   = threadIdx.x >> 6;
    const int lane = threadIdx.x & 63;
    const int fl   = lane % FL;
    const int slot = lane / FL;
    const int node = blockIdx.x * 4 + wv;
    if (node >= N_NODES) return;

    const int beg = offs[node];
    const int end = offs[node + 1];
    const float adn = adst[node];
    const __half* __restrict__ Hf = H16 + fl * 8;

    float s = 0.f;
    float acc[8] = {};

    int eid = beg + slot;
    bool valid = (eid < end);
    unsigned int pk = valid ? csr_pk[eid] : 0u;

    for (int cb = beg; cb < end; cb += SLOTS) {
        const int nid = cb + SLOTS + slot;
        const bool nvalid = (nid < end);
        const unsigned int npk = nvalid ? csr_pk[nid] : 0u;

        float p = 0.f;
        uint4 h = make_uint4(0u, 0u, 0u, 0u);
        if (valid) {
            const unsigned int src = pk & 0xffffu;
            float v = asrc[src] + adn;
            v = fmaxf(v, 0.2f * v);
            p = __expf(fminf(v, 80.f));
            h = *(const uint4*)(Hf + src * DOUT);
        }
        const float2 f0 = __half22float2(*(const __half2*)&h.x);
        const float2 f1 = __half22float2(*(const __half2*)&h.y);
        const float2 f2 = __half22float2(*(const __half2*)&h.z);
        const float2 f3 = __half22float2(*(const __half2*)&h.w);
        s += p;
        acc[0] = fmaf(p, f0.x, acc[0]);
        acc[1] = fmaf(p, f0.y, acc[1]);
        acc[2] = fmaf(p, f1.x, acc[2]);
        acc[3] = fmaf(p, f1.y, acc[3]);
        acc[4] = fmaf(p, f2.x, acc[4]);
        acc[5] = fmaf(p, f2.y, acc[5]);
        acc[6] = fmaf(p, f3.x, acc[6]);
        acc[7] = fmaf(p, f3.y, acc[7]);
        valid = nvalid;
        pk = npk;
    }

#pragma unroll
    for (int off = FL; off < 64; off <<= 1) {
        s += __shfl_xor(s, off, 64);
#pragma unroll
        for (int j = 0; j < 8; ++j)
            acc[j] += __shfl_xor(acc[j], off, 64);
    }

    if (slot == 0) {
        const float inv = 1.f / s;
        float o[8];
#pragma unroll
        for (int j = 0; j < 8; ++j) {
            float v = acc[j] * inv + b[fl * 8 + j];
            o[j] = (ACT == 0) ? fmaxf(v, 0.f) : tanhf(v);
        }
        *(float4*)&out[node * DOUT + fl * 8]     = *(float4*)&o[0];
        *(float4*)&out[node * DOUT + fl * 8 + 4] = *(float4*)&o[4];
    }
}

// ---------------------------------------------------------------------------

extern "C" void kernel_launch(void* const* d_in, const int* in_sizes, int n_in,
                              void* d_out, int out_size, void* d_ws, size_t ws_size,
                              hipStream_t stream)
{
    const float* x  = (const float*)d_in[0];
    const int*   ei = (const int*)d_in[1];
    const float* W0 = (const float*)d_in[2];
    const float* as0= (const float*)d_in[3];
    const float* ad0= (const float*)d_in[4];
    const float* b0 = (const float*)d_in[5];
    const float* W1 = (const float*)d_in[6];
    const float* as1= (const float*)d_in[7];
    const float* ad1= (const float*)d_in[8];
    const float* b1 = (const float*)d_in[9];
    const float* W2 = (const float*)d_in[10];
    const float* as2= (const float*)d_in[11];
    const float* ad2= (const float*)d_in[12];
    const float* b2 = (const float*)d_in[13];
    float* out = (float*)d_out;

    char* wsb = (char*)d_ws;
    auto take = [&](size_t bytes) {
        char* p = wsb;
        wsb += (bytes + 255) & ~size_t(255);
        return p;
    };
    __half* h16a   = (__half*)take(sizeof(__half) * N_NODES * 64);
    __half* h16b   = (__half*)take(sizeof(__half) * N_NODES * 64);
    float* asrc_a  = (float*)take(sizeof(float) * N_NODES);
    float* adst_a  = (float*)take(sizeof(float) * N_NODES);
    float* asrc_b  = (float*)take(sizeof(float) * N_NODES);
    float* adst_b  = (float*)take(sizeof(float) * N_NODES);
    int*   offs    = (int*)take(sizeof(int) * (N_NODES + 1));
    int*   bcnt    = (int*)take(sizeof(int) * NBUCK);
    int*   cur     = (int*)take(sizeof(int) * NBUCK);
    int*   cur0    = (int*)take(sizeof(int) * NBUCK);
    unsigned int* tmp    = (unsigned int*)take(sizeof(unsigned int) * ETOT);
    unsigned int* csr_pk = (unsigned int*)take(sizeof(unsigned int) * ETOT);

    // bcnt must be zero before gemm0's fused hist
    hipMemsetAsync(bcnt, 0, sizeof(int) * NBUCK, stream);

    // gemm0 (x fp32 -> H16_0 + alpha0) with fused edge-bucket histogram
    gemm0_hist_kernel<<<GEMM0_GRID, 256, 0, stream>>>(
        x, W0, as0, ad0, ei, bcnt, h16a, asrc_a, adst_a);

    // CSR build rest
    scan98_kernel<<<1, 128, 0, stream>>>(bcnt, cur, cur0);
    binscatter_kernel<<<BS_NBLK, BS_THREADS, 0, stream>>>(ei, cur, tmp);
    bucket_sort_kernel<<<NBUCK, BUCK_SZ, 0, stream>>>(tmp, cur0, bcnt,
                                                      csr_pk, offs);

    // fused: agg layer0 (relu) + gemm layer1 + alpha1
    fused_agg_gemm_kernel<64><<<GEMM0_GRID, 256, 0, stream>>>(
        offs, csr_pk, asrc_a, adst_a, h16a, b0,
        W1, as1, ad1, h16b, asrc_b, adst_b);

    // fused: agg layer1 (relu) + gemm layer2 + alpha2
    fused_agg_gemm_kernel<32><<<GEMM0_GRID, 256, 0, stream>>>(
        offs, csr_pk, asrc_b, adst_b, h16b, b1,
        W2, as2, ad2, h16a, asrc_a, adst_a);

    // final aggregation + tanh
    const int agg_grid = (N_NODES + 3) / 4;
    node_agg_kernel<32, 1><<<agg_grid, 256, 0, stream>>>(
        offs, csr_pk, asrc_a, adst_a, h16a, b2, out);
}

// Round 12
// 186.473 us; speedup vs baseline: 1.6922x; 1.6922x over previous
//
#include <hip/hip_runtime.h>
#include <hip/hip_fp16.h>
#include <math.h>

#define N_NODES 50000
#define E_EDGES 800000
#define ETOT    (E_EDGES + N_NODES)

// bucketed scatter params
#define BUCK_SHIFT 9
#define BUCK_SZ   (1 << BUCK_SHIFT)                               // 512
#define NBUCK ((N_NODES + BUCK_SZ - 1) >> BUCK_SHIFT)             // 98
#define BS_EPT 16
#define BS_THREADS 256
#define BS_EPB (BS_THREADS * BS_EPT)                              // 4096
#define BS_NBLK ((ETOT + BS_EPB - 1) / BS_EPB)

// gemm0 grid / hist slice
#define GEMM0_GRID ((N_NODES + 63) / 64)                          // 782
#define HPB ((ETOT + GEMM0_GRID - 1) / GEMM0_GRID)                // 1088

// ---------------------------------------------------------------------------
// Layer-0 GEMM + alpha epilogue + fused edge-bucket histogram (r11-verified).
// ---------------------------------------------------------------------------
__global__ __launch_bounds__(256)
void gemm0_hist_kernel(const float* __restrict__ X, const float* __restrict__ W,
                       const float* __restrict__ a_s, const float* __restrict__ a_d,
                       const int* __restrict__ ei, int* __restrict__ bcnt,
                       __half* __restrict__ H16, float* __restrict__ asrc,
                       float* __restrict__ adst)
{
    constexpr int DIN = 128, DOUT = 64;
    constexpr int COLG = DOUT / 4;     // 16
    constexpr int BM   = 64;
    constexpr int K4   = DIN / 4;

    __shared__ float Xl[BM * DIN];     // 32 KB
    __shared__ float Wl[DIN * DOUT];   // 32 KB

    const int tid = threadIdx.x;
    const int row0b = blockIdx.x * BM;

    for (int i = tid; i < DIN * DOUT / 4; i += 256)
        ((float4*)Wl)[i] = ((const float4*)W)[i];

    for (int i = tid; i < BM * K4; i += 256) {
        int r  = i / K4;
        int j  = i % K4;
        int gr = row0b + r;
        float4 v = make_float4(0.f, 0.f, 0.f, 0.f);
        if (gr < N_NODES) v = ((const float4*)X)[gr * K4 + j];
        *(float4*)&Xl[r * DIN + ((j ^ ((r >> 2) & 7)) << 2)] = v;
    }
    __syncthreads();

    const int tx = tid % COLG;
    const int ty = tid / COLG;
    const int r0 = ty * 4;
    const int c0 = tx * 4;
    const int swz = ty & 7;

    float acc[4][4] = {};
    for (int kk = 0; kk < DIN; kk += 4) {
        float a[4][4], w[4][4];
        const int jk = ((kk >> 2) ^ swz) << 2;
#pragma unroll
        for (int i = 0; i < 4; ++i)
            *(float4*)a[i] = *(const float4*)&Xl[(r0 + i) * DIN + jk];
#pragma unroll
        for (int j = 0; j < 4; ++j)
            *(float4*)w[j] = *(const float4*)&Wl[(kk + j) * DOUT + c0];
#pragma unroll
        for (int i = 0; i < 4; ++i)
#pragma unroll
            for (int j = 0; j < 4; ++j)
                acc[i][j] = fmaf(a[i][0], w[0][j],
                            fmaf(a[i][1], w[1][j],
                            fmaf(a[i][2], w[2][j],
                            fmaf(a[i][3], w[3][j], acc[i][j]))));
    }

    float as4[4], ad4[4];
    *(float4*)as4 = *(const float4*)&a_s[c0];
    *(float4*)ad4 = *(const float4*)&a_d[c0];

#pragma unroll
    for (int i = 0; i < 4; ++i) {
        const int gr = row0b + r0 + i;
        float ps = acc[i][0] * as4[0] + acc[i][1] * as4[1] +
                   acc[i][2] * as4[2] + acc[i][3] * as4[3];
        float pd = acc[i][0] * ad4[0] + acc[i][1] * ad4[1] +
                   acc[i][2] * ad4[2] + acc[i][3] * ad4[3];
#pragma unroll
        for (int off = COLG / 2; off >= 1; off >>= 1) {
            ps += __shfl_xor(ps, off, 64);
            pd += __shfl_xor(pd, off, 64);
        }
        if (gr < N_NODES) {
            __half2 p01 = __floats2half2_rn(acc[i][0], acc[i][1]);
            __half2 p23 = __floats2half2_rn(acc[i][2], acc[i][3]);
            uint2 pk;
            pk.x = *(unsigned int*)&p01;
            pk.y = *(unsigned int*)&p23;
            *(uint2*)&H16[gr * DOUT + c0] = pk;
            if (tx == 0) { asrc[gr] = ps; adst[gr] = pd; }
        }
    }

    // ---- fused hist: reuse Xl as LDS counters ----
    __syncthreads();
    int* lh = (int*)Xl;
    for (int i = tid; i < NBUCK; i += 256) lh[i] = 0;
    __syncthreads();
    const int h0 = blockIdx.x * HPB;
    const int hend = min(h0 + HPB, ETOT);
    for (int eid = h0 + tid; eid < hend; eid += 256) {
        int dst = (eid < E_EDGES) ? ei[E_EDGES + eid] : (eid - E_EDGES);
        atomicAdd(&lh[dst >> BUCK_SHIFT], 1);
    }
    __syncthreads();
    for (int i = tid; i < NBUCK; i += 256)
        if (lh[i] > 0) atomicAdd(&bcnt[i], lh[i]);
}

// ---------------------------------------------------------------------------
// Generic GEMM + alpha (layers 1,2). Same as round 10.
// ---------------------------------------------------------------------------
template<int DIN, int DOUT>
__global__ __launch_bounds__(256)
void gemm_alpha_kernel(const float* __restrict__ X, const float* __restrict__ W,
                       const float* __restrict__ a_s, const float* __restrict__ a_d,
                       __half* __restrict__ H16, float* __restrict__ asrc,
                       float* __restrict__ adst)
{
    constexpr int COLG = DOUT / 4;
    constexpr int ROWG = 256 / COLG;
    constexpr int BM   = ROWG * 4;
    constexpr int K4   = DIN / 4;

    __shared__ float Xl[BM * DIN];
    __shared__ float Wl[DIN * DOUT];

    const int tid = threadIdx.x;
    const int row0b = blockIdx.x * BM;

    for (int i = tid; i < DIN * DOUT / 4; i += 256)
        ((float4*)Wl)[i] = ((const float4*)W)[i];

    for (int i = tid; i < BM * K4; i += 256) {
        int r  = i / K4;
        int j  = i % K4;
        int gr = row0b + r;
        float4 v = make_float4(0.f, 0.f, 0.f, 0.f);
        if (gr < N_NODES) v = ((const float4*)X)[gr * K4 + j];
        *(float4*)&Xl[r * DIN + ((j ^ ((r >> 2) & 7)) << 2)] = v;
    }
    __syncthreads();

    const int tx = tid % COLG;
    const int ty = tid / COLG;
    const int r0 = ty * 4;
    const int c0 = tx * 4;
    const int swz = ty & 7;

    float acc[4][4] = {};
    for (int kk = 0; kk < DIN; kk += 4) {
        float a[4][4], w[4][4];
        const int jk = ((kk >> 2) ^ swz) << 2;
#pragma unroll
        for (int i = 0; i < 4; ++i)
            *(float4*)a[i] = *(const float4*)&Xl[(r0 + i) * DIN + jk];
#pragma unroll
        for (int j = 0; j < 4; ++j)
            *(float4*)w[j] = *(const float4*)&Wl[(kk + j) * DOUT + c0];
#pragma unroll
        for (int i = 0; i < 4; ++i)
#pragma unroll
            for (int j = 0; j < 4; ++j)
                acc[i][j] = fmaf(a[i][0], w[0][j],
                            fmaf(a[i][1], w[1][j],
                            fmaf(a[i][2], w[2][j],
                            fmaf(a[i][3], w[3][j], acc[i][j]))));
    }

    float as4[4], ad4[4];
    *(float4*)as4 = *(const float4*)&a_s[c0];
    *(float4*)ad4 = *(const float4*)&a_d[c0];

#pragma unroll
    for (int i = 0; i < 4; ++i) {
        const int gr = row0b + r0 + i;
        float ps = acc[i][0] * as4[0] + acc[i][1] * as4[1] +
                   acc[i][2] * as4[2] + acc[i][3] * as4[3];
        float pd = acc[i][0] * ad4[0] + acc[i][1] * ad4[1] +
                   acc[i][2] * ad4[2] + acc[i][3] * ad4[3];
#pragma unroll
        for (int off = COLG / 2; off >= 1; off >>= 1) {
            ps += __shfl_xor(ps, off, 64);
            pd += __shfl_xor(pd, off, 64);
        }
        if (gr < N_NODES) {
            __half2 p01 = __floats2half2_rn(acc[i][0], acc[i][1]);
            __half2 p23 = __floats2half2_rn(acc[i][2], acc[i][3]);
            uint2 pk;
            pk.x = *(unsigned int*)&p01;
            pk.y = *(unsigned int*)&p23;
            *(uint2*)&H16[gr * DOUT + c0] = pk;
            if (tx == 0) { asrc[gr] = ps; adst[gr] = pd; }
        }
    }
}

// ---------------------------------------------------------------------------
// binscatter with LOCAL scan of bcnt (scan98 dispatch eliminated).
// cur[] is zero-initialized; reservation = base[bk] + atomicAdd(cur[bk]).
// ---------------------------------------------------------------------------
__global__ __launch_bounds__(BS_THREADS)
void binscatter_kernel(const int* __restrict__ ei, const int* __restrict__ bcnt,
                       int* __restrict__ cur, unsigned int* __restrict__ tmp)
{
    __shared__ int lcnt[NBUCK];
    __shared__ int lbase[NBUCK];
    __shared__ int lscan[128];
    const int t = threadIdx.x;

    // local exclusive scan of bcnt -> lbase (bucket bases in csr/tmp)
    if (t < 128) {
        const int v = (t < NBUCK) ? bcnt[t] : 0;
        lscan[t] = v;
        __syncthreads();
        for (int off = 1; off < 128; off <<= 1) {
            int u = (t >= off) ? lscan[t - off] : 0;
            __syncthreads();
            lscan[t] += u;
            __syncthreads();
        }
        if (t < NBUCK) lbase[t] = lscan[t] - v;
    } else {
        __syncthreads();
        for (int off = 1; off < 128; off <<= 1) { __syncthreads(); __syncthreads(); }
    }
    for (int i = t; i < NBUCK; i += BS_THREADS) lcnt[i] = 0;
    __syncthreads();

    const int e0 = blockIdx.x * BS_EPB;
    unsigned int pk[BS_EPT];
    int rk[BS_EPT];
    int bk[BS_EPT];
#pragma unroll
    for (int k = 0; k < BS_EPT; ++k) {
        const int eid = e0 + k * BS_THREADS + t;
        bk[k] = -1;
        if (eid < ETOT) {
            int src, dst;
            if (eid < E_EDGES) { src = ei[eid]; dst = ei[E_EDGES + eid]; }
            else               { src = dst = eid - E_EDGES; }
            bk[k] = dst >> BUCK_SHIFT;
            pk[k] = ((unsigned int)dst << 16) | (unsigned int)src;
            rk[k] = atomicAdd(&lcnt[bk[k]], 1);
        }
    }
    __syncthreads();
    // reserve contiguous runs: global base + zero-based global cursor
    for (int i = t; i < NBUCK; i += BS_THREADS)
        if (lcnt[i] > 0) lbase[i] += atomicAdd(&cur[i], lcnt[i]);
    __syncthreads();
#pragma unroll
    for (int k = 0; k < BS_EPT; ++k)
        if (bk[k] >= 0) tmp[lbase[bk[k]] + rk[k]] = pk[k];
}

// ---------------------------------------------------------------------------
// bucket_sort with LOCAL scan of bcnt (cur0 dependency eliminated).
// ---------------------------------------------------------------------------
__global__ __launch_bounds__(BUCK_SZ)
void bucket_sort_kernel(const unsigned int* __restrict__ tmp,
                        const int* __restrict__ bcnt,
                        unsigned int* __restrict__ csr_pk,
                        int* __restrict__ offs)
{
    __shared__ int lcnt[BUCK_SZ];
    __shared__ int loff[BUCK_SZ];
    __shared__ int lcur[BUCK_SZ];
    __shared__ int sbase;
    const int bk = blockIdx.x;
    const int t  = threadIdx.x;

    // local exclusive scan of bcnt to get this bucket's base
    {
        const int v = (t < NBUCK) ? bcnt[t] : 0;
        lcnt[t] = v;
        __syncthreads();
        for (int off = 1; off < 128; off <<= 1) {
            int u = (t >= off && t < 128) ? lcnt[t - off] : 0;
            __syncthreads();
            if (t < 128) lcnt[t] += u;
            __syncthreads();
        }
        if (t == bk) sbase = lcnt[t] - v;   // exclusive prefix at bk
    }
    __syncthreads();
    const int base = sbase;
    const int cnt  = bcnt[bk];

    lcnt[t] = 0;
    __syncthreads();
    for (int i = t; i < cnt; i += BUCK_SZ)
        atomicAdd(&lcnt[(tmp[base + i] >> 16) & (BUCK_SZ - 1)], 1);
    __syncthreads();

    const int v = lcnt[t];
    loff[t] = v;
    __syncthreads();
    for (int off = 1; off < BUCK_SZ; off <<= 1) {
        int u = (t >= off) ? loff[t - off] : 0;
        __syncthreads();
        loff[t] += u;
        __syncthreads();
    }
    const int excl = loff[t] - v;

    const int g = (bk << BUCK_SHIFT) + t;
    if (g <= N_NODES) offs[g] = base + excl;   // tail node writes offs[N]=ETOT

    lcur[t] = excl;
    __syncthreads();
    for (int i = t; i < cnt; i += BUCK_SZ) {
        const unsigned int pk = tmp[base + i];
        const int l = (pk >> 16) & (BUCK_SZ - 1);
        const int pos = atomicAdd(&lcur[l], 1);
        csr_pk[base + pos] = pk;
    }
}

// ---------------------------------------------------------------------------
// node_agg v5 (round-10 verified): inline score, 16B fp16 gathers, prefetch.
// ---------------------------------------------------------------------------
template<int DOUT, int ACT>
__global__ __launch_bounds__(256)
void node_agg_kernel(const int* __restrict__ offs,
                     const unsigned int* __restrict__ csr_pk,
                     const float* __restrict__ asrc,
                     const float* __restrict__ adst,
                     const __half* __restrict__ H16,
                     const float* __restrict__ b,
                     float* __restrict__ out)
{
    constexpr int FL    = DOUT / 8;    // 8 (dout=64) or 4 (dout=32)
    constexpr int SLOTS = 64 / FL;     // 8 or 16
    const int wv   = threadIdx.x >> 6;
    const int lane = threadIdx.x & 63;
    const int fl   = lane % FL;
    const int slot = lane / FL;
    const int node = blockIdx.x * 4 + wv;
    if (node >= N_NODES) return;

    const int beg = offs[node];
    const int end = offs[node + 1];
    const float adn = adst[node];
    const __half* __restrict__ Hf = H16 + fl * 8;

    float s = 0.f;
    float acc[8] = {};

    int eid = beg + slot;
    bool valid = (eid < end);
    unsigned int pk = valid ? csr_pk[eid] : 0u;

    for (int cb = beg; cb < end; cb += SLOTS) {
        const int nid = cb + SLOTS + slot;
        const bool nvalid = (nid < end);
        const unsigned int npk = nvalid ? csr_pk[nid] : 0u;

        float p = 0.f;
        uint4 h = make_uint4(0u, 0u, 0u, 0u);
        if (valid) {
            const unsigned int src = pk & 0xffffu;
            float v = asrc[src] + adn;
            v = fmaxf(v, 0.2f * v);
            p = __expf(fminf(v, 80.f));
            h = *(const uint4*)(Hf + src * DOUT);
        }
        const float2 f0 = __half22float2(*(const __half2*)&h.x);
        const float2 f1 = __half22float2(*(const __half2*)&h.y);
        const float2 f2 = __half22float2(*(const __half2*)&h.z);
        const float2 f3 = __half22float2(*(const __half2*)&h.w);
        s += p;
        acc[0] = fmaf(p, f0.x, acc[0]);
        acc[1] = fmaf(p, f0.y, acc[1]);
        acc[2] = fmaf(p, f1.x, acc[2]);
        acc[3] = fmaf(p, f1.y, acc[3]);
        acc[4] = fmaf(p, f2.x, acc[4]);
        acc[5] = fmaf(p, f2.y, acc[5]);
        acc[6] = fmaf(p, f3.x, acc[6]);
        acc[7] = fmaf(p, f3.y, acc[7]);
        valid = nvalid;
        pk = npk;
    }

#pragma unroll
    for (int off = FL; off < 64; off <<= 1) {
        s += __shfl_xor(s, off, 64);
#pragma unroll
        for (int j = 0; j < 8; ++j)
            acc[j] += __shfl_xor(acc[j], off, 64);
    }

    if (slot == 0) {
        const float inv = 1.f / s;
        float o[8];
#pragma unroll
        for (int j = 0; j < 8; ++j) {
            float v = acc[j] * inv + b[fl * 8 + j];
            o[j] = (ACT == 0) ? fmaxf(v, 0.f) : tanhf(v);
        }
        *(float4*)&out[node * DOUT + fl * 8]     = *(float4*)&o[0];
        *(float4*)&out[node * DOUT + fl * 8 + 4] = *(float4*)&o[4];
    }
}

// ---------------------------------------------------------------------------

extern "C" void kernel_launch(void* const* d_in, const int* in_sizes, int n_in,
                              void* d_out, int out_size, void* d_ws, size_t ws_size,
                              hipStream_t stream)
{
    const float* x  = (const float*)d_in[0];
    const int*   ei = (const int*)d_in[1];
    const float* W0 = (const float*)d_in[2];
    const float* as0= (const float*)d_in[3];
    const float* ad0= (const float*)d_in[4];
    const float* b0 = (const float*)d_in[5];
    const float* W1 = (const float*)d_in[6];
    const float* as1= (const float*)d_in[7];
    const float* ad1= (const float*)d_in[8];
    const float* b1 = (const float*)d_in[9];
    const float* W2 = (const float*)d_in[10];
    const float* as2= (const float*)d_in[11];
    const float* ad2= (const float*)d_in[12];
    const float* b2 = (const float*)d_in[13];
    float* out = (float*)d_out;

    char* wsb = (char*)d_ws;
    auto take = [&](size_t bytes) {
        char* p = wsb;
        wsb += (bytes + 255) & ~size_t(255);
        return p;
    };
    __half* h16    = (__half*)take(sizeof(__half) * N_NODES * 64);
    float* buf_act = (float*)take(sizeof(float) * N_NODES * 64);
    float* asrc    = (float*)take(sizeof(float) * N_NODES);
    float* adst    = (float*)take(sizeof(float) * N_NODES);
    int*   offs    = (int*)take(sizeof(int) * (N_NODES + 1));
    int*   bc      = (int*)take(sizeof(int) * NBUCK * 2);   // bcnt | cur
    int*   bcnt    = bc;
    int*   cur     = bc + NBUCK;
    unsigned int* tmp    = (unsigned int*)take(sizeof(unsigned int) * ETOT);
    unsigned int* csr_pk = (unsigned int*)take(sizeof(unsigned int) * ETOT);

    // one memset: bcnt + cur
    hipMemsetAsync(bc, 0, sizeof(int) * NBUCK * 2, stream);

    // gemm0 (fp32 x -> H16 + alpha0) with fused edge-bucket histogram
    gemm0_hist_kernel<<<GEMM0_GRID, 256, 0, stream>>>(
        x, W0, as0, ad0, ei, bcnt, h16, asrc, adst);

    // CSR build (local scans; no scan98 dispatch)
    binscatter_kernel<<<BS_NBLK, BS_THREADS, 0, stream>>>(ei, bcnt, cur, tmp);
    bucket_sort_kernel<<<NBUCK, BUCK_SZ, 0, stream>>>(tmp, bcnt, csr_pk, offs);

    // layer 0 aggregation (relu) -> buf_act
    const int agg_grid = (N_NODES + 3) / 4;
    node_agg_kernel<64, 0><<<agg_grid, 256, 0, stream>>>(
        offs, csr_pk, asrc, adst, h16, b0, buf_act);

    // layer 1
    gemm_alpha_kernel<64, 64><<<GEMM0_GRID, 256, 0, stream>>>(
        buf_act, W1, as1, ad1, h16, asrc, adst);
    node_agg_kernel<64, 0><<<agg_grid, 256, 0, stream>>>(
        offs, csr_pk, asrc, adst, h16, b1, buf_act);

    // layer 2
    gemm_alpha_kernel<64, 32><<<(N_NODES + 127) / 128, 256, 0, stream>>>(
        buf_act, W2, as2, ad2, h16, asrc, adst);
    node_agg_kernel<32, 1><<<agg_grid, 256, 0, stream>>>(
        offs, csr_pk, asrc, adst, h16, b2, out);
}